// Round 13
// baseline (164.619 us; speedup 1.0000x reference)
//
#include <hip/hip_runtime.h>

typedef _Float16 f16;
typedef _Float16 f16x8 __attribute__((ext_vector_type(8)));
typedef __fp16   fp16x2 __attribute__((ext_vector_type(2)));
typedef float    f32x16 __attribute__((ext_vector_type(16)));
typedef float    f32x4  __attribute__((ext_vector_type(4)));
typedef unsigned int u32;
typedef unsigned int u32x4 __attribute__((ext_vector_type(4)));

#define NPTS 262144

// ---- packed layout in d_ws (per net, net stride NET_F16 f16) ----
// Weight image = 70 contiguous 8KB chunks (512 x u32x4):
//   net0: L0 (1) | L1 (16) | L2 (16) | L3 (2) = 35 chunks; net1 same.
// Chunk contents: frag[mt][lane][8 f16] (L3: frag[kt][lane][8]).
// A-frag (mfma_f32_32x32x16_f16): A[m][k], m = 32*mt + (lane&31);
//   k(L0) = 8*hi + j canonical (zero-padded); k(L1/L2/L3) PERMUTED:
//   kphys(kt,hi,j) = 32*(kt>>1) + 16*(kt&1) + (j&3) + 8*(j>>2) + 4*hi
//   == C/D layout of previous layer's tile -> zero-shuffle epilogue.
// f32 biases at byte BIAS_BYTE, 800 floats/net, packed in C/D order.
#define NET_F16   143360
#define BIAS_BYTE 573440

static __device__ __forceinline__ u32 pkrtz(float a, float b) {
    fp16x2 h = __builtin_amdgcn_cvt_pkrtz(a, b);
    return __builtin_bit_cast(u32, h);
}
static __device__ __forceinline__ u32 relu_pk(float a, float b) {
    return pkrtz(fmaxf(a, 0.0f), fmaxf(b, 0.0f));
}

// ---------------- weight/bias packing kernel (unchanged, proven) ----------------
__global__ void prep_kernel(
    const float* __restrict__ dW0, const float* __restrict__ db0,
    const float* __restrict__ dW1, const float* __restrict__ db1,
    const float* __restrict__ dW2, const float* __restrict__ db2,
    const float* __restrict__ dW3, const float* __restrict__ db3,
    const float* __restrict__ sW0, const float* __restrict__ sb0,
    const float* __restrict__ sW1, const float* __restrict__ sb1,
    const float* __restrict__ sW2, const float* __restrict__ sb2,
    const float* __restrict__ sW3, const float* __restrict__ sb3,
    f16* __restrict__ wpk, float* __restrict__ bpk)
{
    const int ROWS = 17920;
    int t = blockIdx.x * 256 + threadIdx.x;
    if (t < 2 * ROWS) {
        int net = (t >= ROWS) ? 1 : 0;
        int r = t - net * ROWS;
        const float* W0 = net ? sW0 : dW0;
        const float* W1 = net ? sW1 : dW1;
        const float* W2 = net ? sW2 : dW2;
        const float* W3 = net ? sW3 : dW3;
        int K0 = net ? 8 : 3;
        f16* o = wpk + net * NET_F16;
        if (r < 512) {                                   // L0: canonical slots
            int lane = r & 63;
            int m  = 32 * (r >> 6) + (lane & 31);
            int kb = 8 * (lane >> 5);
            f16* q = o + r * 8;
            #pragma unroll
            for (int j = 0; j < 8; ++j) {
                int k = kb + j;
                q[j] = (f16)((k < K0) ? W0[k * 256 + m] : 0.0f);
            }
        } else if (r < 512 + 8192) {                     // L1: permuted k
            int rr = r - 512;
            int lane = rr & 63;
            int hh = lane >> 5;
            int m  = 32 * ((rr >> 6) & 7) + (lane & 31);
            int kt = rr >> 9;
            f16* q = o + 4096 + rr * 8;
            #pragma unroll
            for (int j = 0; j < 8; ++j) {
                int kp = 32 * (kt >> 1) + 16 * (kt & 1) + (j & 3) + 8 * (j >> 2) + 4 * hh;
                q[j] = (f16)W1[kp * 256 + m];
            }
        } else if (r < 512 + 16384) {                    // L2: permuted k
            int rr = r - (512 + 8192);
            int lane = rr & 63;
            int hh = lane >> 5;
            int m  = 32 * ((rr >> 6) & 7) + (lane & 31);
            int kt = rr >> 9;
            f16* q = o + 69632 + rr * 8;
            #pragma unroll
            for (int j = 0; j < 8; ++j) {
                int kp = 32 * (kt >> 1) + 16 * (kt & 1) + (j & 3) + 8 * (j >> 2) + 4 * hh;
                q[j] = (f16)W2[kp * 256 + m];
            }
        } else {                                         // L3: permuted k
            int rr = r - (512 + 16384);
            int lane = rr & 63;
            int hh = lane >> 5;
            int m  = lane & 31;
            int kt = rr >> 6;
            f16* q = o + 135168 + rr * 8;
            #pragma unroll
            for (int j = 0; j < 8; ++j) {
                int kp = 32 * (kt >> 1) + 16 * (kt & 1) + (j & 3) + 8 * (j >> 2) + 4 * hh;
                q[j] = (f16)((m < 3) ? W3[kp * 3 + m] : 0.0f);
            }
        }
    } else if (t < 2 * ROWS + 1600) {                    // biases (C/D order)
        int tb = t - 2 * ROWS;
        int net = (tb >= 800) ? 1 : 0;
        int i = tb - net * 800;
        float val;
        if (i < 768) {
            int layer = i >> 8;
            const float* bl = net ? (layer == 0 ? sb0 : layer == 1 ? sb1 : sb2)
                                  : (layer == 0 ? db0 : layer == 1 ? db1 : db2);
            int q  = i & 255;
            int rg = q & 15, h = (q >> 4) & 1;
            int m  = 32 * (q >> 5) + (rg & 3) + 8 * (rg >> 2) + 4 * h;
            val = bl[m];
        } else {
            int q  = i - 768;
            int rg = q & 15, h = q >> 4;
            int m  = (rg & 3) + 8 * (rg >> 2) + 4 * h;
            const float* b3 = net ? sb3 : db3;
            val = (m < 3) ? b3[m] : 0.0f;
        }
        bpk[net * 800 + i] = val;
    }
}

// Issue the full 8KB chunk G into this wave's ring slot (G&3): 8 lane-linear
// 16B DMAs. Wave-private destination -> no cross-wave hazards ever.
#define DMA8(G) do {                                                            \
    const u32x4* g_ = ws + (G) * 512 + lane;                                    \
    u32x4* l_ = &stage[wv][(G) & 3][0];                                         \
    _Pragma("unroll")                                                           \
    for (int i_ = 0; i_ < 8; ++i_)                                              \
        __builtin_amdgcn_global_load_lds(                                       \
            (const __attribute__((address_space(1))) void*)(g_ + i_ * 64),      \
            (__attribute__((address_space(3))) void*)(l_ + i_ * 64), 16, 0, 0); \
} while (0)

// Counted wait: WS = allowed outstanding DMA loads (3 batches x 8 = 24 steady).
// sched_barrier stops ds_reads of the waited-on chunk hoisting above the wait.
#define VWAIT(WS) do {                                                          \
    asm volatile("s_waitcnt vmcnt(" WS ")" ::: "memory");                       \
    __builtin_amdgcn_sched_barrier(0);                                          \
} while (0)

// Steady-state step header: prefetch chunk G+3 (depth-3), wait chunk G landed.
#define STEP24(G) do { DMA8((G) + 3); VWAIT("24"); } while (0)

// One 256x256 chunk (global idx G), K-tile KT: 8 A-frags, each feeds both
// point-sets (pt=2). All register indices compile-time (rule #20).
#define CH256(G, KT) do {                                                       \
    const u32x4* bq_ = &stage[wv][(G) & 3][0];                                  \
    const f16x8 xA_ = __builtin_bit_cast(f16x8, xf0[KT]);                       \
    const f16x8 xB_ = __builtin_bit_cast(f16x8, xf1[KT]);                       \
    _Pragma("unroll")                                                           \
    for (int mt_ = 0; mt_ < 8; ++mt_) {                                         \
        const f16x8 a_ = __builtin_bit_cast(f16x8, bq_[mt_ * 64 + lane]);       \
        acc0[mt_] = __builtin_amdgcn_mfma_f32_32x32x16_f16(a_, xA_, acc0[mt_], 0, 0, 0); \
        acc1[mt_] = __builtin_amdgcn_mfma_f32_32x32x16_f16(a_, xB_, acc1[mt_], 0, 0, 0); \
    }                                                                           \
} while (0)

// L3 chunk (global idx G): 8 kt-frags x both c3 accumulators, xf base HB.
#define L3C(G, HB) do {                                                         \
    const u32x4* bq_ = &stage[wv][(G) & 3][0];                                  \
    _Pragma("unroll")                                                           \
    for (int i_ = 0; i_ < 8; ++i_) {                                            \
        const f16x8 a_ = __builtin_bit_cast(f16x8, bq_[i_ * 64 + lane]);        \
        c30 = __builtin_amdgcn_mfma_f32_32x32x16_f16(a_, __builtin_bit_cast(f16x8, xf0[(HB) + i_]), c30, 0, 0, 0); \
        c31 = __builtin_amdgcn_mfma_f32_32x32x16_f16(a_, __builtin_bit_cast(f16x8, xf1[(HB) + i_]), c31, 0, 0, 0); \
    }                                                                           \
} while (0)

#define BINIT(dst, boff) do {                                                   \
    const f32x4* b4_ = (const f32x4*)(biasl + (boff) + hi * 16);                \
    const f32x4 v0_ = b4_[0], v1_ = b4_[1], v2_ = b4_[2], v3_ = b4_[3];         \
    _Pragma("unroll")                                                           \
    for (int j = 0; j < 4; ++j) {                                               \
        (dst)[j] = v0_[j]; (dst)[4 + j] = v1_[j];                               \
        (dst)[8 + j] = v2_[j]; (dst)[12 + j] = v3_[j];                          \
    }                                                                           \
} while (0)

#define EPI1(ACC, XF) do {                                                      \
    _Pragma("unroll")                                                           \
    for (int mt = 0; mt < 8; ++mt) {                                            \
        _Pragma("unroll")                                                       \
        for (int q = 0; q < 2; ++q) {                                           \
            u32x4 w;                                                            \
            w[0] = relu_pk(ACC[mt][8*q+0], ACC[mt][8*q+1]);                     \
            w[1] = relu_pk(ACC[mt][8*q+2], ACC[mt][8*q+3]);                     \
            w[2] = relu_pk(ACC[mt][8*q+4], ACC[mt][8*q+5]);                     \
            w[3] = relu_pk(ACC[mt][8*q+6], ACC[mt][8*q+7]);                     \
            XF[2*mt+q] = w;                                                     \
        }                                                                       \
    }                                                                           \
} while (0)
#define EPI() do { EPI1(acc0, xf0); EPI1(acc1, xf1); } while (0)

// ---------------- fused dual-MLP kernel ----------------
// 256 thr = 4 waves, 64 points/wave (pt=2), grid 1024. ZERO barriers after
// the prologue sync: each wave streams all 70 chunks through its PRIVATE
// 4-slot LDS ring (depth-3 counted vmcnt). Waves self-stagger -> LDS pipe
// and MFMA pipe overlap across waves without lockstep drains.
__launch_bounds__(256, 1)
__global__ void mlp_kernel(const float* __restrict__ gn, const float* __restrict__ gv,
                           const float* __restrict__ gro, const float* __restrict__ gr0,
                           const f16* __restrict__ wpk, const float* __restrict__ bpk,
                           float* __restrict__ out)
{
    __shared__ u32x4 stage[4][4][512];             // [wave][slot][8KB] = 128KB
    __shared__ __align__(16) float biasl[1600];    // 6.4KB biases

    const int tid  = threadIdx.x;
    const int wv   = tid >> 6;
    const int lane = tid & 63;
    const int l32  = lane & 31;
    const int hi   = lane >> 5;
    const int pA   = blockIdx.x * 256 + wv * 64 + l32;
    const int pB   = pA + 32;
    const u32x4* ws = (const u32x4*)wpk;           // 70-chunk contiguous stream

    // ---- biases -> LDS (published by the single barrier below) ----
    biasl[tid]        = bpk[tid];
    biasl[tid + 256]  = bpk[tid + 256];
    biasl[tid + 512]  = bpk[tid + 512];
    biasl[tid + 768]  = bpk[tid + 768];
    biasl[tid + 1024] = bpk[tid + 1024];
    biasl[tid + 1280] = bpk[tid + 1280];
    if (tid < 64) biasl[tid + 1536] = bpk[tid + 1536];

    // ---- inputs for both points (before DMA: keeps vmcnt window pure) ----
    u32x4 xdA = {0,0,0,0}, xsA = {0,0,0,0}, xdB = {0,0,0,0}, xsB = {0,0,0,0};
    bool visA = false, visB = false;
    if (hi == 0) {
        {
            float nx = gn[3*pA], ny = gn[3*pA+1], nz = gn[3*pA+2];
            float vx = gv[3*pA], vy = gv[3*pA+1], vz = gv[3*pA+2];
            float ro = gro[pA], rr = gr0[pA];
            float ni = 1.0f / fmaxf(sqrtf(nx*nx + ny*ny + nz*nz), 1e-12f);
            float vi = 1.0f / fmaxf(sqrtf(vx*vx + vy*vy + vz*vz), 1e-12f);
            nx *= ni; ny *= ni; nz *= ni; vx *= vi; vy *= vi; vz *= vi;
            visA = (nx*vx + ny*vy + nz*vz) > 0.0f;
            xdA[0] = pkrtz(nx, ny); xdA[1] = pkrtz(nz, 0.0f);
            xsA[0] = xdA[0];        xsA[1] = pkrtz(nz, vx);
            xsA[2] = pkrtz(vy, vz); xsA[3] = pkrtz(ro, rr);
        }
        {
            float nx = gn[3*pB], ny = gn[3*pB+1], nz = gn[3*pB+2];
            float vx = gv[3*pB], vy = gv[3*pB+1], vz = gv[3*pB+2];
            float ro = gro[pB], rr = gr0[pB];
            float ni = 1.0f / fmaxf(sqrtf(nx*nx + ny*ny + nz*nz), 1e-12f);
            float vi = 1.0f / fmaxf(sqrtf(vx*vx + vy*vy + vz*vz), 1e-12f);
            nx *= ni; ny *= ni; nz *= ni; vx *= vi; vy *= vi; vz *= vi;
            visB = (nx*vx + ny*vy + nz*vz) > 0.0f;
            xdB[0] = pkrtz(nx, ny); xdB[1] = pkrtz(nz, 0.0f);
            xsB[0] = xdB[0];        xsB[1] = pkrtz(nz, vx);
            xsB[2] = pkrtz(vy, vz); xsB[3] = pkrtz(ro, rr);
        }
    }

    // Single barrier: drains input loads (vmcnt->0) and publishes biasl.
    __syncthreads();

    // ---- depth-3 prologue: chunks 0,1,2 in flight ----
    DMA8(0);
    DMA8(1);
    DMA8(2);

    f32x16 acc0[8], acc1[8];   // 256 regs -> AGPR half of unified file
    u32x4  xf0[16], xf1[16];   // 128 VGPRs

    #pragma unroll
    for (int net = 0; net < 2; ++net) {
        const int cb = net * 35;
        const int bb = net * 800;
        const f16x8 xhA = __builtin_bit_cast(f16x8, net ? xsA : xdA);
        const f16x8 xhB = __builtin_bit_cast(f16x8, net ? xsB : xdB);

        // ---- s0: L0 ----
        STEP24(cb + 0);
        {
            const u32x4* bufq = &stage[wv][(cb + 0) & 3][0];
            #pragma unroll
            for (int mt = 0; mt < 8; ++mt) {
                f32x16 ci;
                BINIT(ci, bb + mt * 32);
                const f16x8 a = __builtin_bit_cast(f16x8, bufq[mt * 64 + lane]);
                acc0[mt] = __builtin_amdgcn_mfma_f32_32x32x16_f16(a, xhA, ci, 0, 0, 0);
                acc1[mt] = __builtin_amdgcn_mfma_f32_32x32x16_f16(a, xhB, ci, 0, 0, 0);
            }
        }
        EPI();

        // ---- s1..16: L1 ----
        #pragma unroll
        for (int mt = 0; mt < 8; ++mt) { BINIT(acc0[mt], bb + 256 + mt * 32); BINIT(acc1[mt], bb + 256 + mt * 32); }
        #pragma unroll
        for (int s = 1; s <= 16; ++s) {
            STEP24(cb + s);
            CH256(cb + s, s - 1);
        }
        EPI();

        // ---- s17..32: L2 (s32 is the last chunk with a prefetch target for net1) ----
        #pragma unroll
        for (int mt = 0; mt < 8; ++mt) { BINIT(acc0[mt], bb + 512 + mt * 32); BINIT(acc1[mt], bb + 512 + mt * 32); }
        #pragma unroll
        for (int s = 17; s <= 31; ++s) {
            STEP24(cb + s);
            CH256(cb + s, s - 17);
        }
        if (net == 0) { STEP24(32); } else { VWAIT("16"); }   // g=67: chunks 68,69 in flight
        CH256(cb + 32, 15);
        EPI();

        // ---- s33,34: L3 ----
        {
            f32x16 c30, c31;
            BINIT(c30, bb + 768);
            BINIT(c31, bb + 768);
            if (net == 0) { STEP24(33); } else { VWAIT("8"); }  // g=68
            L3C(cb + 33, 0);
            if (net == 0) { STEP24(34); } else { VWAIT("0"); }  // g=69: full drain
            L3C(cb + 34, 8);
            if (hi == 0) {
                float* opA = out + net * (NPTS * 3) + pA * 3;
                float* opB = out + net * (NPTS * 3) + pB * 3;
                opA[0] = visA ? c30[0] : 0.0f;
                opA[1] = visA ? c30[1] : 0.0f;
                opA[2] = visA ? c30[2] : 0.0f;
                opB[0] = visB ? c31[0] : 0.0f;
                opB[1] = visB ? c31[1] : 0.0f;
                opB[2] = visB ? c31[2] : 0.0f;
            }
        }
    }
}

extern "C" void kernel_launch(void* const* d_in, const int* in_sizes, int n_in,
                              void* d_out, int out_size, void* d_ws, size_t ws_size,
                              hipStream_t stream)
{
    f16*   wpk = (f16*)d_ws;
    float* bpk = (float*)((char*)d_ws + BIAS_BYTE);

    prep_kernel<<<147, 256, 0, stream>>>(
        (const float*)d_in[4],  (const float*)d_in[5],
        (const float*)d_in[6],  (const float*)d_in[7],
        (const float*)d_in[8],  (const float*)d_in[9],
        (const float*)d_in[10], (const float*)d_in[11],
        (const float*)d_in[12], (const float*)d_in[13],
        (const float*)d_in[14], (const float*)d_in[15],
        (const float*)d_in[16], (const float*)d_in[17],
        (const float*)d_in[18], (const float*)d_in[19],
        wpk, bpk);

    mlp_kernel<<<1024, 256, 0, stream>>>(
        (const float*)d_in[0], (const float*)d_in[1],
        (const float*)d_in[2], (const float*)d_in[3],
        wpk, bpk, (float*)d_out);
}

// Round 14
// 149.032 us; speedup vs baseline: 1.1046x; 1.1046x over previous
//
#include <hip/hip_runtime.h>

typedef _Float16 f16;
typedef _Float16 f16x8 __attribute__((ext_vector_type(8)));
typedef __fp16   fp16x2 __attribute__((ext_vector_type(2)));
typedef float    f32x16 __attribute__((ext_vector_type(16)));
typedef float    f32x4  __attribute__((ext_vector_type(4)));
typedef unsigned int u32;
typedef unsigned int u32x4 __attribute__((ext_vector_type(4)));

#define NPTS 262144

// ---- packed layout in d_ws (per net, net stride NET_F16 f16) ----
// Weight image = 70 contiguous 8KB chunks (512 x u32x4):
//   net0: L0 (1) | L1 (16) | L2 (16) | L3 (2) = 35 chunks; net1 same.
// Chunk contents: frag[mt][lane][8 f16] (L3: frag[kt][lane][8]).
// A-frag (mfma_f32_32x32x16_f16): A[m][k], m = 32*mt + (lane&31);
//   k(L0) = 8*hi + j canonical (zero-padded); k(L1/L2/L3) PERMUTED:
//   kphys(kt,hi,j) = 32*(kt>>1) + 16*(kt&1) + (j&3) + 8*(j>>2) + 4*hi
//   == C/D layout of previous layer's tile -> zero-shuffle epilogue.
// f32 biases at byte BIAS_BYTE, 800 floats/net, packed in C/D order.
#define NET_F16   143360
#define BIAS_BYTE 573440

static __device__ __forceinline__ u32 pkrtz(float a, float b) {
    fp16x2 h = __builtin_amdgcn_cvt_pkrtz(a, b);
    return __builtin_bit_cast(u32, h);
}
static __device__ __forceinline__ u32 relu_pk(float a, float b) {
    return pkrtz(fmaxf(a, 0.0f), fmaxf(b, 0.0f));
}

// ---------------- weight/bias packing kernel (unchanged, proven) ----------------
__global__ void prep_kernel(
    const float* __restrict__ dW0, const float* __restrict__ db0,
    const float* __restrict__ dW1, const float* __restrict__ db1,
    const float* __restrict__ dW2, const float* __restrict__ db2,
    const float* __restrict__ dW3, const float* __restrict__ db3,
    const float* __restrict__ sW0, const float* __restrict__ sb0,
    const float* __restrict__ sW1, const float* __restrict__ sb1,
    const float* __restrict__ sW2, const float* __restrict__ sb2,
    const float* __restrict__ sW3, const float* __restrict__ sb3,
    f16* __restrict__ wpk, float* __restrict__ bpk)
{
    const int ROWS = 17920;
    int t = blockIdx.x * 256 + threadIdx.x;
    if (t < 2 * ROWS) {
        int net = (t >= ROWS) ? 1 : 0;
        int r = t - net * ROWS;
        const float* W0 = net ? sW0 : dW0;
        const float* W1 = net ? sW1 : dW1;
        const float* W2 = net ? sW2 : dW2;
        const float* W3 = net ? sW3 : dW3;
        int K0 = net ? 8 : 3;
        f16* o = wpk + net * NET_F16;
        if (r < 512) {                                   // L0: canonical slots
            int lane = r & 63;
            int m  = 32 * (r >> 6) + (lane & 31);
            int kb = 8 * (lane >> 5);
            f16* q = o + r * 8;
            #pragma unroll
            for (int j = 0; j < 8; ++j) {
                int k = kb + j;
                q[j] = (f16)((k < K0) ? W0[k * 256 + m] : 0.0f);
            }
        } else if (r < 512 + 8192) {                     // L1: permuted k
            int rr = r - 512;
            int lane = rr & 63;
            int hh = lane >> 5;
            int m  = 32 * ((rr >> 6) & 7) + (lane & 31);
            int kt = rr >> 9;
            f16* q = o + 4096 + rr * 8;
            #pragma unroll
            for (int j = 0; j < 8; ++j) {
                int kp = 32 * (kt >> 1) + 16 * (kt & 1) + (j & 3) + 8 * (j >> 2) + 4 * hh;
                q[j] = (f16)W1[kp * 256 + m];
            }
        } else if (r < 512 + 16384) {                    // L2: permuted k
            int rr = r - (512 + 8192);
            int lane = rr & 63;
            int hh = lane >> 5;
            int m  = 32 * ((rr >> 6) & 7) + (lane & 31);
            int kt = rr >> 9;
            f16* q = o + 69632 + rr * 8;
            #pragma unroll
            for (int j = 0; j < 8; ++j) {
                int kp = 32 * (kt >> 1) + 16 * (kt & 1) + (j & 3) + 8 * (j >> 2) + 4 * hh;
                q[j] = (f16)W2[kp * 256 + m];
            }
        } else {                                         // L3: permuted k
            int rr = r - (512 + 16384);
            int lane = rr & 63;
            int hh = lane >> 5;
            int m  = lane & 31;
            int kt = rr >> 6;
            f16* q = o + 135168 + rr * 8;
            #pragma unroll
            for (int j = 0; j < 8; ++j) {
                int kp = 32 * (kt >> 1) + 16 * (kt & 1) + (j & 3) + 8 * (j >> 2) + 4 * hh;
                q[j] = (f16)((m < 3) ? W3[kp * 3 + m] : 0.0f);
            }
        }
    } else if (t < 2 * ROWS + 1600) {                    // biases (C/D order)
        int tb = t - 2 * ROWS;
        int net = (tb >= 800) ? 1 : 0;
        int i = tb - net * 800;
        float val;
        if (i < 768) {
            int layer = i >> 8;
            const float* bl = net ? (layer == 0 ? sb0 : layer == 1 ? sb1 : sb2)
                                  : (layer == 0 ? db0 : layer == 1 ? db1 : db2);
            int q  = i & 255;
            int rg = q & 15, h = (q >> 4) & 1;
            int m  = 32 * (q >> 5) + (rg & 3) + 8 * (rg >> 2) + 4 * h;
            val = bl[m];
        } else {
            int q  = i - 768;
            int rg = q & 15, h = q >> 4;
            int m  = (rg & 3) + 8 * (rg >> 2) + 4 * h;
            const float* b3 = net ? sb3 : db3;
            val = (m < 3) ? b3[m] : 0.0f;
        }
        bpk[net * 800 + i] = val;
    }
}

// Counted-wait + barrier (T3/T4): WS = allowed in-flight loads (one future
// batch). lgkmcnt(0)+sched_barrier before s_barrier = rule-18 fence.
// EXACT R12 protocol (numerically proven at 4-wave blocks).
#define WAITB(WS) do {                                                          \
    asm volatile("s_waitcnt vmcnt(" WS ") lgkmcnt(0)" ::: "memory");            \
    __builtin_amdgcn_sched_barrier(0);                                          \
    __builtin_amdgcn_s_barrier();                                               \
    __builtin_amdgcn_sched_barrier(0);                                          \
} while (0)

// Stage 1 / 2 chunks into ring slot S (wave wv moves rows woff..woff+127).
#define STAGE1(S, C0) do {                                                      \
    const u32x4* g_ = ws + (C0) * 512 + woff + lane;                            \
    u32x4* l_ = &ring[S][woff];                                                 \
    __builtin_amdgcn_global_load_lds(                                           \
        (const __attribute__((address_space(1))) void*)g_,                      \
        (__attribute__((address_space(3))) void*)l_, 16, 0, 0);                 \
    __builtin_amdgcn_global_load_lds(                                           \
        (const __attribute__((address_space(1))) void*)(g_ + 64),               \
        (__attribute__((address_space(3))) void*)(l_ + 64), 16, 0, 0);          \
} while (0)
#define STAGE2(S, C0) do {                                                      \
    _Pragma("unroll")                                                           \
    for (int i_ = 0; i_ < 2; ++i_) {                                            \
        const u32x4* g_ = ws + ((C0) + i_) * 512 + woff + lane;                 \
        u32x4* l_ = &ring[S][i_ * 512 + woff];                                  \
        __builtin_amdgcn_global_load_lds(                                       \
            (const __attribute__((address_space(1))) void*)g_,                  \
            (__attribute__((address_space(3))) void*)l_, 16, 0, 0);             \
        __builtin_amdgcn_global_load_lds(                                       \
            (const __attribute__((address_space(1))) void*)(g_ + 64),           \
            (__attribute__((address_space(3))) void*)(l_ + 64), 16, 0, 0);      \
    }                                                                           \
} while (0)

// One 256x256 chunk at ring[S][CI*512], K-tile KT (pt=1: 8 MFMA, 8 ds_read).
#define CHUNK256(S, CI, KT) do {                                                \
    const u32x4* bq_ = &ring[S][(CI) * 512];                                    \
    const f16x8 xh_ = __builtin_bit_cast(f16x8, xf[KT]);                        \
    _Pragma("unroll")                                                           \
    for (int mt_ = 0; mt_ < 8; ++mt_) {                                         \
        const f16x8 a_ = __builtin_bit_cast(f16x8, bq_[mt_ * 64 + lane]);       \
        acc[mt_] = __builtin_amdgcn_mfma_f32_32x32x16_f16(a_, xh_, acc[mt_], 0, 0, 0); \
    }                                                                           \
} while (0)

#define BINIT(dst, boff) do {                                                   \
    const f32x4* b4_ = (const f32x4*)(biasl + (boff) + hi * 16);                \
    const f32x4 v0_ = b4_[0], v1_ = b4_[1], v2_ = b4_[2], v3_ = b4_[3];         \
    _Pragma("unroll")                                                           \
    for (int j = 0; j < 4; ++j) {                                               \
        (dst)[j] = v0_[j]; (dst)[4 + j] = v1_[j];                               \
        (dst)[8 + j] = v2_[j]; (dst)[12 + j] = v3_[j];                          \
    }                                                                           \
} while (0)

// Zero-shuffle epilogue (static indices only, rule #20).
#define EPI() do {                                                              \
    _Pragma("unroll")                                                           \
    for (int mt = 0; mt < 8; ++mt) {                                            \
        _Pragma("unroll")                                                       \
        for (int q = 0; q < 2; ++q) {                                           \
            u32x4 w;                                                            \
            w[0] = relu_pk(acc[mt][8*q+0], acc[mt][8*q+1]);                     \
            w[1] = relu_pk(acc[mt][8*q+2], acc[mt][8*q+3]);                     \
            w[2] = relu_pk(acc[mt][8*q+4], acc[mt][8*q+5]);                     \
            w[3] = relu_pk(acc[mt][8*q+6], acc[mt][8*q+7]);                     \
            xf[2*mt+q] = w;                                                     \
        }                                                                       \
    }                                                                           \
} while (0)

// ---------------- fused dual-MLP kernel ----------------
// 256 thr = 4 waves, 32 points/wave (pt=1), grid 2048, 2 blocks/CU ->
// 8 waves/CU (2/SIMD). R12's counted-vmcnt no-drain pipeline (3-slot ring,
// depth-2, 2-chunk steps): TLP hides latency, counted waits avoid drains.
__launch_bounds__(256, 2)
__global__ void mlp_kernel(const float* __restrict__ gn, const float* __restrict__ gv,
                           const float* __restrict__ gro, const float* __restrict__ gr0,
                           const f16* __restrict__ wpk, const float* __restrict__ bpk,
                           float* __restrict__ out)
{
    __shared__ u32x4 ring[3][1024];                // 3 x 16KB slots = 48KB
    __shared__ __align__(16) float biasl[1600];    // 6.4KB biases

    const int tid  = threadIdx.x;
    const int wv   = tid >> 6;
    const int lane = tid & 63;
    const int l32  = lane & 31;
    const int hi   = lane >> 5;
    const int p    = blockIdx.x * 128 + wv * 32 + l32;
    const int woff = wv * 128;
    const u32x4* ws = (const u32x4*)wpk;           // 70-chunk contiguous stream

    // ---- biases -> LDS ----
    biasl[tid]        = bpk[tid];
    biasl[tid + 256]  = bpk[tid + 256];
    biasl[tid + 512]  = bpk[tid + 512];
    biasl[tid + 768]  = bpk[tid + 768];
    biasl[tid + 1024] = bpk[tid + 1024];
    biasl[tid + 1280] = bpk[tid + 1280];
    if (tid < 64) biasl[tid + 1536] = bpk[tid + 1536];

    // ---- inputs BEFORE the pipeline (keeps the counted vmcnt window pure) ----
    u32x4 xd = {0,0,0,0}, xs = {0,0,0,0};
    bool vis = false;
    if (hi == 0) {               // hi lanes hold k=8..15 (zero-padded)
        float nx = gn[3*p], ny = gn[3*p+1], nz = gn[3*p+2];
        float vx = gv[3*p], vy = gv[3*p+1], vz = gv[3*p+2];
        float ro = gro[p], rr = gr0[p];
        float ni = 1.0f / fmaxf(sqrtf(nx*nx + ny*ny + nz*nz), 1e-12f);
        float vi = 1.0f / fmaxf(sqrtf(vx*vx + vy*vy + vz*vz), 1e-12f);
        nx *= ni; ny *= ni; nz *= ni; vx *= vi; vy *= vi; vz *= vi;
        vis = (nx*vx + ny*vy + nz*vz) > 0.0f;
        xd[0] = pkrtz(nx, ny); xd[1] = pkrtz(nz, 0.0f);
        xs[0] = xd[0];         xs[1] = pkrtz(nz, vx);
        xs[2] = pkrtz(vy, vz); xs[3] = pkrtz(ro, rr);
    }

    // drain input/bias traffic, publish biasl (single full sync, pre-pipeline)
    __syncthreads();

    // ---- pipeline prologue: batches for steps 0 (L0: 2 loads) and 1 (4) ----
    STAGE1(0, 0);
    STAGE2(1, 1);

    f32x16 acc[8];    // 128 regs -> AGPRs
    u32x4  xf[16];    // 64 VGPRs

    #pragma unroll
    for (int net = 0; net < 2; ++net) {
        const int cb = net * 35;
        const int bb = net * 800;
        const f16x8 xh0 = __builtin_bit_cast(f16x8, net ? xs : xd);

        // ---- t=0: L0 (slot 0); stage t=2 (chunks cb+3,4 -> slot 2) ----
        WAITB("4");
        STAGE2(2, cb + 3);
        {
            const u32x4* bufq = &ring[0][0];
            #pragma unroll
            for (int mt = 0; mt < 8; ++mt) {
                f32x16 ci;
                BINIT(ci, bb + mt * 32);
                const f16x8 a = __builtin_bit_cast(f16x8, bufq[mt * 64 + lane]);
                acc[mt] = __builtin_amdgcn_mfma_f32_32x32x16_f16(a, xh0, ci, 0, 0, 0);
            }
        }
        EPI();

        // ---- t=1..8: L1 (chunks cb+2t-1, cb+2t from slot t%3) ----
        #pragma unroll
        for (int mt = 0; mt < 8; ++mt) BINIT(acc[mt], bb + 256 + mt * 32);
        #pragma unroll
        for (int t = 1; t <= 8; ++t) {
            WAITB("4");
            STAGE2((t + 2) % 3, cb + 2 * t + 3);       // batch for step t+2
            CHUNK256(t % 3, 0, 2 * t - 2);
            CHUNK256(t % 3, 1, 2 * t - 1);
        }
        EPI();

        // ---- t=9..16: L2 ----
        #pragma unroll
        for (int mt = 0; mt < 8; ++mt) BINIT(acc[mt], bb + 512 + mt * 32);
        #pragma unroll
        for (int t = 9; t <= 15; ++t) {
            WAITB("4");
            STAGE2((t + 2) % 3, cb + 2 * t + 3);       // t=15 stages L3 (cb+33,34)
            CHUNK256(t % 3, 0, 2 * t - 18);
            CHUNK256(t % 3, 1, 2 * t - 17);
        }
        // t=16: stages next net's L0 (step 18 -> slot 0)
        WAITB("4");
        if (net == 0) STAGE1(0, 35);
        CHUNK256(16 % 3, 0, 14);
        CHUNK256(16 % 3, 1, 15);
        EPI();

        // ---- t=17: L3 (chunks cb+33,34 from slot 2); stage next net's t=1 ----
        if (net == 0) { WAITB("2"); STAGE2(1, 36); }
        else          { WAITB("0"); }
        {
            f32x16 c3;
            BINIT(c3, bb + 768);
            const u32x4* bq0 = &ring[2][0];
            const u32x4* bq1 = &ring[2][512];
            #pragma unroll
            for (int i = 0; i < 8; ++i) {
                const f16x8 a = __builtin_bit_cast(f16x8, bq0[i * 64 + lane]);
                c3 = __builtin_amdgcn_mfma_f32_32x32x16_f16(a, __builtin_bit_cast(f16x8, xf[i]), c3, 0, 0, 0);
            }
            #pragma unroll
            for (int i = 0; i < 8; ++i) {
                const f16x8 a = __builtin_bit_cast(f16x8, bq1[i * 64 + lane]);
                c3 = __builtin_amdgcn_mfma_f32_32x32x16_f16(a, __builtin_bit_cast(f16x8, xf[8 + i]), c3, 0, 0, 0);
            }
            if (hi == 0) {
                float* op = out + net * (NPTS * 3) + p * 3;
                op[0] = vis ? c3[0] : 0.0f;
                op[1] = vis ? c3[1] : 0.0f;
                op[2] = vis ? c3[2] : 0.0f;
            }
        }
    }
}

extern "C" void kernel_launch(void* const* d_in, const int* in_sizes, int n_in,
                              void* d_out, int out_size, void* d_ws, size_t ws_size,
                              hipStream_t stream)
{
    f16*   wpk = (f16*)d_ws;
    float* bpk = (float*)((char*)d_ws + BIAS_BYTE);

    prep_kernel<<<147, 256, 0, stream>>>(
        (const float*)d_in[4],  (const float*)d_in[5],
        (const float*)d_in[6],  (const float*)d_in[7],
        (const float*)d_in[8],  (const float*)d_in[9],
        (const float*)d_in[10], (const float*)d_in[11],
        (const float*)d_in[12], (const float*)d_in[13],
        (const float*)d_in[14], (const float*)d_in[15],
        (const float*)d_in[16], (const float*)d_in[17],
        (const float*)d_in[18], (const float*)d_in[19],
        wpk, bpk);

    mlp_kernel<<<2048, 256, 0, stream>>>(
        (const float*)d_in[0], (const float*)d_in[1],
        (const float*)d_in[2], (const float*)d_in[3],
        wpk, bpk, (float*)d_out);
}